// Round 16
// baseline (374.681 us; speedup 1.0000x reference)
//
#include <hip/hip_runtime.h>

typedef __attribute__((ext_vector_type(8))) __bf16 bf16x8;
typedef __attribute__((ext_vector_type(4))) float f32x4;
typedef __attribute__((ext_vector_type(4))) int i32x4;
typedef __attribute__((ext_vector_type(8))) unsigned short ushort8;

#define T_TOKENS 8192
#define K_DIM    4096
#define N_DIM    4096
#define NGRP     32
#define GS       128

__device__ __forceinline__ unsigned short f2bf(float f) {
  unsigned u = __builtin_bit_cast(unsigned, f);
  u += 0x7fffu + ((u >> 16) & 1u);   // round-to-nearest-even (inputs are finite)
  return (unsigned short)(u >> 16);
}

__device__ __forceinline__ f32x4 mfma16(bf16x8 a, bf16x8 b, f32x4 c) {
  return __builtin_amdgcn_mfma_f32_16x16x32_bf16(a, b, c, 0, 0, 0);
}

__device__ __forceinline__ i32x4 mfma_i8(i32x4 a, i32x4 b, i32x4 c) {
  return __builtin_amdgcn_mfma_i32_16x16x64_i8(a, b, c, 0, 0, 0);
}

__device__ __forceinline__ void gload_lds16(const void* g, void* l) {
  __builtin_amdgcn_global_load_lds(
      (const __attribute__((address_space(1))) void*)g,
      (__attribute__((address_space(3))) void*)l, 16, 0, 0);
}

__device__ __forceinline__ int clamp127(int q) {
  return q > 127 ? 127 : (q < -127 ? -127 : q);
}

// ---------------- Kernel 1: fused prep ---------------------------------------
// Blocks 0..63   : fold+wquant — block b owns rows b*64..b*64+63 across ALL 32
//                  groups: computes W_eff (bf16, spilled to global), tracks the
//                  per-row absmax locally (no atomics), then re-reads its own
//                  L2-hot slice and writes qw int8 + swf. Placed first so the
//                  heavy blocks dispatch early.
// Blocks 64..2111: per-row int8 quantization of x (wave = row, true absmax).
__global__ __launch_bounds__(256) void k_prep(const float* __restrict__ x,
                                              signed char* __restrict__ qx,
                                              float* __restrict__ sxf,
                                              const int* __restrict__ idxp,
                                              const float* __restrict__ cb,
                                              const float* __restrict__ norms,
                                              const float* __restrict__ rot,
                                              unsigned short* __restrict__ weff,
                                              signed char* __restrict__ qw,
                                              float* __restrict__ swf) {
  __shared__ unsigned short Rt[128][136];
  __shared__ unsigned short Wq[64][136];
  __shared__ float cbl[16];
  __shared__ float ldsmax[2][64];
  const int tid = threadIdx.x;

  if (blockIdx.x >= 64) {  // ---- x quant: wave = row ----
    const int wid = (blockIdx.x - 64) * 4 + (tid >> 6);
    const int l = tid & 63;
    const float* xr = x + (size_t)wid * K_DIM;
    float4 v[16];
    float am = 0.f;
    #pragma unroll
    for (int i = 0; i < 16; ++i) {
      v[i] = *reinterpret_cast<const float4*>(xr + (i * 64 + l) * 4);
      am = fmaxf(am, fmaxf(fmaxf(fabsf(v[i].x), fabsf(v[i].y)),
                           fmaxf(fabsf(v[i].z), fabsf(v[i].w))));
    }
    #pragma unroll
    for (int m = 1; m < 64; m <<= 1) am = fmaxf(am, __shfl_xor(am, m, 64));
    const float inv = am > 0.f ? 127.0f / am : 0.f;
    #pragma unroll
    for (int i = 0; i < 16; ++i) {
      int q0 = clamp127(__float2int_rn(v[i].x * inv));
      int q1 = clamp127(__float2int_rn(v[i].y * inv));
      int q2 = clamp127(__float2int_rn(v[i].z * inv));
      int q3 = clamp127(__float2int_rn(v[i].w * inv));
      unsigned d = (q0 & 255) | ((q1 & 255) << 8) | ((q2 & 255) << 16) |
                   ((unsigned)(q3 & 255) << 24);
      *reinterpret_cast<unsigned*>(qx + (size_t)wid * K_DIM + (size_t)(i * 64 + l) * 4) = d;
    }
    if (l == 0) sxf[wid] = am * (1.0f / 127.0f);
    return;
  }

  // ---- fold + wquant: block owns 64 rows x all groups ----
  const int b = blockIdx.x;                 // row tile (0..63)
  const int nbase = b * 64;
  if (tid < 16) cbl[tid] = cb[tid];

  const int w = tid >> 6, l = tid & 63;
  const int wm = w >> 1, wn = w & 1;        // 2M x 2N waves; wave tile 32x64
  const int rl = l & 15, hi = l >> 4;

  float rmax[2][4] = {{0.f, 0.f, 0.f, 0.f}, {0.f, 0.f, 0.f, 0.f}};
  const float inv_scale = 0.088388347648318447f;  // 1/sqrt(128)

  for (int g = 0; g < NGRP; ++g) {
    __syncthreads();   // previous group's LDS reads complete before overwrite
    { // stage R_g transposed into LDS as bf16 (thread -> row j, half kh)
      const int j = tid >> 1, kh = (tid & 1) * 64;
      const float* rp = rot + ((size_t)g * 128 + j) * 128 + kh;
      #pragma unroll
      for (int c = 0; c < 64; c += 4) {
        float4 vv = *reinterpret_cast<const float4*>(rp + c);
        Rt[kh + c + 0][j] = f2bf(vv.x);
        Rt[kh + c + 1][j] = f2bf(vv.y);
        Rt[kh + c + 2][j] = f2bf(vv.z);
        Rt[kh + c + 3][j] = f2bf(vv.w);
      }
    }
    { // decode packed 4-bit codes: thread -> row nl, quarter qt (16 ints)
      const int nl = tid >> 2, qt = tid & 3;
      const int* ip = idxp + ((size_t)(nbase + nl)) * (K_DIM / 2) + g * 64 + qt * 16;
      #pragma unroll
      for (int c = 0; c < 16; c += 4) {
        int4 vv = *reinterpret_cast<const int4*>(ip + c);
        int va[4] = {vv.x, vv.y, vv.z, vv.w};
        #pragma unroll
        for (int q = 0; q < 4; ++q) {
          int bb = va[q] & 0xFF;
          Wq[nl][qt * 32 + (c + q) * 2 + 0] = f2bf(cbl[bb & 0xF]);
          Wq[nl][qt * 32 + (c + q) * 2 + 1] = f2bf(cbl[(bb >> 4) & 0xF]);
        }
      }
    }
    __syncthreads();

    f32x4 acc[2][4] = {};
    #pragma unroll
    for (int ks = 0; ks < 4; ++ks) {
      bf16x8 a0 = *(const bf16x8*)&Wq[wm * 32 +  0 + rl][ks * 32 + hi * 8];
      bf16x8 a1 = *(const bf16x8*)&Wq[wm * 32 + 16 + rl][ks * 32 + hi * 8];
      #pragma unroll
      for (int nc = 0; nc < 4; ++nc) {
        bf16x8 bfr = *(const bf16x8*)&Rt[wn * 64 + nc * 16 + rl][ks * 32 + hi * 8];
        acc[0][nc] = mfma16(a0, bfr, acc[0][nc]);
        acc[1][nc] = mfma16(a1, bfr, acc[1][nc]);
      }
    }

    #pragma unroll
    for (int m = 0; m < 2; ++m) {
      const int r0 = nbase + wm * 32 + m * 16 + hi * 4;
      float nv[4];
      #pragma unroll
      for (int r = 0; r < 4; ++r) nv[r] = norms[(size_t)(r0 + r) * NGRP + g] * inv_scale;
      #pragma unroll
      for (int nc = 0; nc < 4; ++nc) {
        #pragma unroll
        for (int r = 0; r < 4; ++r) {
          float wv = acc[m][nc][r] * nv[r];
          weff[(size_t)(r0 + r) * K_DIM + g * GS + wn * 64 + nc * 16 + rl] = f2bf(wv);
          rmax[m][r] = fmaxf(rmax[m][r], fabsf(wv));
        }
      }
    }
  }

  // reduce rmax over the 16 col-lanes, publish per-row max to LDS
  #pragma unroll
  for (int m = 0; m < 2; ++m) {
    #pragma unroll
    for (int r = 0; r < 4; ++r) {
      float v = rmax[m][r];
      #pragma unroll
      for (int msk = 1; msk < 16; msk <<= 1) v = fmaxf(v, __shfl_xor(v, msk, 64));
      if (rl == 0) ldsmax[wn][wm * 32 + m * 16 + hi * 4 + r] = v;
    }
  }
  __syncthreads();   // also orders this block's weff global writes (same CU/L1)

  // quantize own 64 rows: thread -> row t>>2, col quarter (1024 cols)
  {
    const int lr = tid >> 2, qt = tid & 3;
    const int n = nbase + lr;
    const float am = fmaxf(ldsmax[0][lr], ldsmax[1][lr]);
    const float inv = am > 0.f ? 127.0f / am : 0.f;
    const unsigned short* wr = weff + (size_t)n * K_DIM + qt * 1024;
    signed char* qr = qw + (size_t)n * K_DIM + qt * 1024;
    #pragma unroll 4
    for (int c = 0; c < 1024; c += 16) {
      ushort8 u0 = *(const ushort8*)(wr + c);
      ushort8 u1 = *(const ushort8*)(wr + c + 8);
      unsigned d[4];
      #pragma unroll
      for (int j = 0; j < 2; ++j) {
        ushort8 u = j ? u1 : u0;
        #pragma unroll
        for (int h = 0; h < 2; ++h) {
          int q0 = clamp127(__float2int_rn(__uint_as_float((unsigned)u[h * 4 + 0] << 16) * inv));
          int q1 = clamp127(__float2int_rn(__uint_as_float((unsigned)u[h * 4 + 1] << 16) * inv));
          int q2 = clamp127(__float2int_rn(__uint_as_float((unsigned)u[h * 4 + 2] << 16) * inv));
          int q3 = clamp127(__float2int_rn(__uint_as_float((unsigned)u[h * 4 + 3] << 16) * inv));
          d[j * 2 + h] = (q0 & 255) | ((q1 & 255) << 8) | ((q2 & 255) << 16) |
                         ((unsigned)(q3 & 255) << 24);
        }
      }
      *reinterpret_cast<int4*>(qr + c) = make_int4((int)d[0], (int)d[1], (int)d[2], (int)d[3]);
    }
    if (qt == 0) swf[n] = am * (1.0f / 127.0f);
  }
}

// ---------------- Kernel 2: 256x256 8-phase int8 GEMM (R10-exact) -----------
// BM=BN=256, BK=128 i8, 512 threads = 8 waves (2M x 4N). Same XOR swizzle,
// staging map, vmcnt(4) at phases 3/7. 16 iters x 8 phases; 16 MFMA/phase.
// Epilogue: out = sx[row] * sw[col] * (float)acc_i32.
#define VMW asm volatile("s_waitcnt vmcnt(4)" ::: "memory")
#define NOW ((void)0)

#define STG(gbase, koff, ldsoff) do { \
    gload_lds16((gbase) + (size_t)(koff), &lds[(ldsoff) + dst0]); \
    gload_lds16((gbase) + (size_t)(koff) + (size_t)64 * K_DIM, \
                &lds[(ldsoff) + dst0 + 4096]); \
  } while (0)

#define PHASE(qq, PAR, TAIL, ...) { \
    if ((qq) == 0) { \
      const int bb = 32768 + (PAR) * 16384 + (wc >> 1) * 8192 + ((wc & 1) * 64 + rl) * 64; \
      _Pragma("unroll") \
      for (int n = 0; n < 4; ++n) { \
        bfr[n][0] = *(const i32x4*)&lds[bb + n * 1024 + slot0]; \
        bfr[n][1] = *(const i32x4*)&lds[bb + n * 1024 + slot1]; \
      } \
    } \
    { const int ab = (PAR) * 16384 + wr * 8192 + ((qq) * 32 + rl) * 64; \
      af00 = *(const i32x4*)&lds[ab + slot0]; \
      af01 = *(const i32x4*)&lds[ab + slot1]; \
      af10 = *(const i32x4*)&lds[ab + 1024 + slot0]; \
      af11 = *(const i32x4*)&lds[ab + 1024 + slot1]; } \
    __VA_ARGS__; \
    asm volatile("s_barrier" ::: "memory"); \
    __builtin_amdgcn_s_setprio(1); \
    _Pragma("unroll") \
    for (int n = 0; n < 4; ++n) { \
      acc[(qq)*2][n]     = mfma_i8(af01, bfr[n][1], \
                             mfma_i8(af00, bfr[n][0], acc[(qq)*2][n])); \
      acc[(qq)*2 + 1][n] = mfma_i8(af11, bfr[n][1], \
                             mfma_i8(af10, bfr[n][0], acc[(qq)*2 + 1][n])); \
    } \
    __builtin_amdgcn_s_setprio(0); \
    TAIL; \
    asm volatile("s_barrier" ::: "memory"); \
  }

__global__ __launch_bounds__(512) void k_gemm(const signed char* __restrict__ A,
                                              const signed char* __restrict__ Bw,
                                              const float* __restrict__ sxf,
                                              const float* __restrict__ swf,
                                              float* __restrict__ C) {
  __shared__ unsigned short lds[65536];   // 128 KiB
  const int tid = threadIdx.x;
  const int l = tid & 63, w = tid >> 6;
  const int wr = w >> 2, wc = w & 3;      // 2M x 4N waves
  const int rl = l & 15, hi = l >> 4;

  // XCD-aware remap: 8x8 tile chunk per XCD (proven R9)
  const int bid = blockIdx.x;
  const int xcd = bid & 7, jj = bid >> 3;
  const int brow = ((xcd >> 1) * 8 + (jj >> 3)) * 256;   // 32 m-tiles
  const int bcol = ((xcd & 1) * 8 + (jj & 7)) * 256;     // 16 n-tiles

  // staging: per-thread source with inverse swizzle, linear LDS dest
  const int row0 = tid >> 3;                                // 0..63
  const int gc = ((tid & 7) ^ (row0 & 7)) * 16;             // pre-swizzled byte col
  const signed char* pa  = A  + (size_t)(brow + row0) * K_DIM + gc;
  const signed char* pa2 = pa + (size_t)128 * K_DIM;
  const signed char* pb  = Bw + (size_t)(bcol + row0) * K_DIM + gc;
  const signed char* pb2 = pb + (size_t)128 * K_DIM;
  const int dst0 = tid * 8;   // ushort units = 16B per thread

  // swizzled ds_read slot offsets (ushort units; row&7 == rl&7 for our rows)
  const int rb7 = rl & 7;
  const int slot0 = ((0 + hi) ^ rb7) << 3;   // kh=0 (k 0..63)
  const int slot1 = ((4 + hi) ^ rb7) << 3;   // kh=1 (k 64..127)

  i32x4 acc[8][4] = {};

  // ---- prologue: stage B(0), A(0), B(1) ----
  STG(pb,  0,   32768);           // B(0).h0
  STG(pb2, 0,   32768 + 8192);    // B(0).h1
  STG(pa,  0,   0);               // A(0).h0
  STG(pa2, 0,   8192);            // A(0).h1
  STG(pb,  128, 32768 + 16384);          // B(1).h0
  STG(pb2, 128, 32768 + 16384 + 8192);   // B(1).h1
  asm volatile("s_waitcnt vmcnt(4)" ::: "memory");
  asm volatile("s_barrier" ::: "memory");

  for (int it = 0; it < 16; ++it) {
    const int k0  = it * 256;
    const int kA1 = k0 + 128;                     // tile 2it+1
    const int kN0 = (k0 + 256) & (K_DIM - 1);     // tile 2it+2 (wrapped at end)
    const int kN1 = (k0 + 384) & (K_DIM - 1);     // tile 2it+3
    i32x4 bfr[4][2];
    i32x4 af00, af01, af10, af11;
    PHASE(0, 0, NOW, STG(pa,  kA1, 16384))                 // stage A(2it+1).h0
    PHASE(1, 0, NOW, STG(pa2, kA1, 16384 + 8192))          // A(2it+1).h1
    PHASE(2, 0, NOW, STG(pb,  kN0, 32768))                 // B(2it+2).h0
    PHASE(3, 0, VMW, STG(pb2, kN0, 32768 + 8192))          // B(2it+2).h1
    PHASE(0, 1, NOW, STG(pa,  kN0, 0))                     // A(2it+2).h0
    PHASE(1, 1, NOW, STG(pa2, kN0, 8192))                  // A(2it+2).h1
    PHASE(2, 1, NOW, STG(pb,  kN1, 32768 + 16384))         // B(2it+3).h0
    PHASE(3, 1, VMW, STG(pb2, kN1, 32768 + 16384 + 8192))  // B(2it+3).h1
  }

  // epilogue: dequant out = sx[row] * sw[col] * acc
  float swv[4];
  #pragma unroll
  for (int n = 0; n < 4; ++n) swv[n] = swf[bcol + wc * 64 + n * 16 + rl];
  #pragma unroll
  for (int m = 0; m < 8; ++m) {
    const int row = brow + wr * 128 + m * 16 + hi * 4;
    float sxr[4];
    #pragma unroll
    for (int r = 0; r < 4; ++r) sxr[r] = sxf[row + r];
    #pragma unroll
    for (int n = 0; n < 4; ++n) {
      const int col = bcol + wc * 64 + n * 16 + rl;
      #pragma unroll
      for (int r = 0; r < 4; ++r)
        C[(size_t)(row + r) * N_DIM + col] = (float)acc[m][n][r] * sxr[r] * swv[n];
    }
  }
}

extern "C" void kernel_launch(void* const* d_in, const int* in_sizes, int n_in,
                              void* d_out, int out_size, void* d_ws, size_t ws_size,
                              hipStream_t stream) {
  const float* x     = (const float*)d_in[0];
  const int*   idxp  = (const int*)d_in[1];
  const float* cb    = (const float*)d_in[2];
  const float* norms = (const float*)d_in[3];
  const float* rot   = (const float*)d_in[4];
  float* out = (float*)d_out;

  unsigned short* weff = (unsigned short*)d_ws;                            // 32 MiB
  signed char* qw  = (signed char*)d_ws + 33554432;                        // 16 MiB
  signed char* qx  = (signed char*)d_ws + 50331648;                        // 32 MiB
  float* sxf   = (float*)((char*)d_ws + 83886080);                         // 32 KiB
  float* swf   = (float*)((char*)d_ws + 83935232);                         // 16 KiB

  k_prep<<<2112, 256, 0, stream>>>(x, qx, sxf, idxp, cb, norms, rot, weff, qw, swf);
  k_gemm<<<512, 512, 0, stream>>>(qx, qw, sxf, swf, out);
}

// Round 17
// 199.094 us; speedup vs baseline: 1.8819x; 1.8819x over previous
//
#include <hip/hip_runtime.h>

typedef __attribute__((ext_vector_type(8))) __bf16 bf16x8;
typedef __attribute__((ext_vector_type(4))) float f32x4;
typedef __attribute__((ext_vector_type(4))) int i32x4;
typedef __attribute__((ext_vector_type(8))) unsigned short ushort8;

#define T_TOKENS 8192
#define K_DIM    4096
#define N_DIM    4096
#define NGRP     32
#define GS       128

__device__ __forceinline__ unsigned short f2bf(float f) {
  unsigned u = __builtin_bit_cast(unsigned, f);
  u += 0x7fffu + ((u >> 16) & 1u);   // round-to-nearest-even (inputs are finite)
  return (unsigned short)(u >> 16);
}

__device__ __forceinline__ f32x4 mfma16(bf16x8 a, bf16x8 b, f32x4 c) {
  return __builtin_amdgcn_mfma_f32_16x16x32_bf16(a, b, c, 0, 0, 0);
}

__device__ __forceinline__ i32x4 mfma_i8(i32x4 a, i32x4 b, i32x4 c) {
  return __builtin_amdgcn_mfma_i32_16x16x64_i8(a, b, c, 0, 0, 0);
}

__device__ __forceinline__ void gload_lds16(const void* g, void* l) {
  __builtin_amdgcn_global_load_lds(
      (const __attribute__((address_space(1))) void*)g,
      (__attribute__((address_space(3))) void*)l, 16, 0, 0);
}

__device__ __forceinline__ int clamp127(int q) {
  return q > 127 ? 127 : (q < -127 ? -127 : q);
}

// ---------------- Kernel 1: fused x-int8-quant + fold (R10-proven) ----------
// Blocks 0..2047: per-row int8 quantization of x (1 wave per row, true absmax).
// Blocks 2048..3071: fold codebook+rotation+norm -> W_eff bf16; block (nt,g)
// uniquely owns (rows nt*128..+127, group g) and writes its per-row partial
// max to swpart[n][g] (no atomics, no memset needed).
__global__ __launch_bounds__(256) void k_prep(const float* __restrict__ x,
                                              signed char* __restrict__ qx,
                                              float* __restrict__ sxf,
                                              const int* __restrict__ idxp,
                                              const float* __restrict__ cb,
                                              const float* __restrict__ norms,
                                              const float* __restrict__ rot,
                                              unsigned short* __restrict__ weff,
                                              float* __restrict__ swpart) {
  __shared__ unsigned short Rt[128][136];
  __shared__ unsigned short Wq[128][136];
  __shared__ float cbl[16];
  const int tid = threadIdx.x;

  if (blockIdx.x < 2048) {  // ---- x quant: wave = row ----
    const int wid = blockIdx.x * 4 + (tid >> 6);
    const int l = tid & 63;
    const float* xr = x + (size_t)wid * K_DIM;
    float4 v[16];
    float am = 0.f;
    #pragma unroll
    for (int i = 0; i < 16; ++i) {
      v[i] = *reinterpret_cast<const float4*>(xr + (i * 64 + l) * 4);
      am = fmaxf(am, fmaxf(fmaxf(fabsf(v[i].x), fabsf(v[i].y)),
                           fmaxf(fabsf(v[i].z), fabsf(v[i].w))));
    }
    #pragma unroll
    for (int m = 1; m < 64; m <<= 1) am = fmaxf(am, __shfl_xor(am, m, 64));
    const float inv = am > 0.f ? 127.0f / am : 0.f;
    #pragma unroll
    for (int i = 0; i < 16; ++i) {
      int q0 = clamp127(__float2int_rn(v[i].x * inv));
      int q1 = clamp127(__float2int_rn(v[i].y * inv));
      int q2 = clamp127(__float2int_rn(v[i].z * inv));
      int q3 = clamp127(__float2int_rn(v[i].w * inv));
      unsigned d = (q0 & 255) | ((q1 & 255) << 8) | ((q2 & 255) << 16) |
                   ((unsigned)(q3 & 255) << 24);
      *reinterpret_cast<unsigned*>(qx + (size_t)wid * K_DIM + (size_t)(i * 64 + l) * 4) = d;
    }
    if (l == 0) sxf[wid] = am * (1.0f / 127.0f);
    return;
  }

  // ---- fold part ----
  const int v = blockIdx.x - 2048;
  const int nt = v & 31;   // n-tile (0..31)
  const int g  = v >> 5;   // group  (0..31)
  if (tid < 16) cbl[tid] = cb[tid];

  { // stage R_g transposed into LDS as bf16
    const int j = tid >> 1, kh = (tid & 1) * 64;
    const float* rp = rot + ((size_t)g * 128 + j) * 128 + kh;
    #pragma unroll
    for (int c = 0; c < 64; c += 4) {
      float4 vv = *reinterpret_cast<const float4*>(rp + c);
      Rt[kh + c + 0][j] = f2bf(vv.x);
      Rt[kh + c + 1][j] = f2bf(vv.y);
      Rt[kh + c + 2][j] = f2bf(vv.z);
      Rt[kh + c + 3][j] = f2bf(vv.w);
    }
  }
  __syncthreads();

  { // decode packed 4-bit codes -> bf16 codebook values
    const int nl = tid >> 1, hf = (tid & 1);
    const int* ip = idxp + ((size_t)(nt * 128 + nl)) * (K_DIM / 2) + g * 64 + hf * 32;
    #pragma unroll
    for (int c = 0; c < 32; c += 4) {
      int4 vv = *reinterpret_cast<const int4*>(ip + c);
      int va[4] = {vv.x, vv.y, vv.z, vv.w};
      #pragma unroll
      for (int q = 0; q < 4; ++q) {
        int b = va[q] & 0xFF;
        Wq[nl][hf * 64 + (c + q) * 2 + 0] = f2bf(cbl[b & 0xF]);
        Wq[nl][hf * 64 + (c + q) * 2 + 1] = f2bf(cbl[(b >> 4) & 0xF]);
      }
    }
  }
  __syncthreads();

  const int w = tid >> 6, l = tid & 63;
  const int rl = l & 15, hi = l >> 4;
  f32x4 acc[2][8] = {};
  #pragma unroll
  for (int ks = 0; ks < 4; ++ks) {
    bf16x8 a0 = *(const bf16x8*)&Wq[w * 32 +  0 + rl][ks * 32 + hi * 8];
    bf16x8 a1 = *(const bf16x8*)&Wq[w * 32 + 16 + rl][ks * 32 + hi * 8];
    #pragma unroll
    for (int nc = 0; nc < 8; ++nc) {
      bf16x8 bfr = *(const bf16x8*)&Rt[nc * 16 + rl][ks * 32 + hi * 8];
      acc[0][nc] = mfma16(a0, bfr, acc[0][nc]);
      acc[1][nc] = mfma16(a1, bfr, acc[1][nc]);
    }
  }

  const float inv_scale = 0.088388347648318447f;  // 1/sqrt(128)
  #pragma unroll
  for (int m = 0; m < 2; ++m) {
    const int r0 = nt * 128 + w * 32 + m * 16 + hi * 4;
    float nv[4];
    #pragma unroll
    for (int r = 0; r < 4; ++r) nv[r] = norms[(size_t)(r0 + r) * NGRP + g] * inv_scale;
    float rowmax[4] = {0.f, 0.f, 0.f, 0.f};
    #pragma unroll
    for (int nc = 0; nc < 8; ++nc) {
      #pragma unroll
      for (int r = 0; r < 4; ++r) {
        float wv = acc[m][nc][r] * nv[r];
        weff[(size_t)(r0 + r) * K_DIM + g * GS + nc * 16 + rl] = f2bf(wv);
        rowmax[r] = fmaxf(rowmax[r], fabsf(wv));
      }
    }
    #pragma unroll
    for (int r = 0; r < 4; ++r) {
      #pragma unroll
      for (int msk = 1; msk < 16; msk <<= 1)
        rowmax[r] = fmaxf(rowmax[r], __shfl_xor(rowmax[r], msk, 64));
      if (rl == 0) swpart[(size_t)(r0 + r) * NGRP + g] = rowmax[r];
    }
  }
}

// ---------------- Kernel 2: W_eff bf16 -> int8 (per-row scale) --------------
// Row max = reduce of the 32 per-group partials (unique-writer array).
__global__ __launch_bounds__(256) void k_wquant(const unsigned short* __restrict__ weff,
                                                const float* __restrict__ swpart,
                                                signed char* __restrict__ qw,
                                                float* __restrict__ swf) {
  const int n = blockIdx.x, t = threadIdx.x;
  const float* sp = swpart + (size_t)n * NGRP;
  float am = 0.f;
  #pragma unroll
  for (int i = 0; i < NGRP; i += 4) {
    float4 pv = *reinterpret_cast<const float4*>(sp + i);
    am = fmaxf(am, fmaxf(fmaxf(pv.x, pv.y), fmaxf(pv.z, pv.w)));
  }
  const float inv = am > 0.f ? 127.0f / am : 0.f;
  const unsigned short* wr = weff + (size_t)n * K_DIM + t * 16;
  ushort8 u0 = *(const ushort8*)wr;
  ushort8 u1 = *(const ushort8*)(wr + 8);
  unsigned d[4];
  #pragma unroll
  for (int j = 0; j < 2; ++j) {
    ushort8 u = j ? u1 : u0;
    #pragma unroll
    for (int h = 0; h < 2; ++h) {
      int q0 = clamp127(__float2int_rn(__uint_as_float((unsigned)u[h * 4 + 0] << 16) * inv));
      int q1 = clamp127(__float2int_rn(__uint_as_float((unsigned)u[h * 4 + 1] << 16) * inv));
      int q2 = clamp127(__float2int_rn(__uint_as_float((unsigned)u[h * 4 + 2] << 16) * inv));
      int q3 = clamp127(__float2int_rn(__uint_as_float((unsigned)u[h * 4 + 3] << 16) * inv));
      d[j * 2 + h] = (q0 & 255) | ((q1 & 255) << 8) | ((q2 & 255) << 16) |
                     ((unsigned)(q3 & 255) << 24);
    }
  }
  *reinterpret_cast<int4*>(qw + (size_t)n * K_DIM + t * 16) =
      make_int4((int)d[0], (int)d[1], (int)d[2], (int)d[3]);
  if (t == 0) swf[n] = am * (1.0f / 127.0f);
}

// ---------------- Kernel 3: 256x256 8-phase int8 GEMM (R10-exact) -----------
// BM=BN=256, BK=128 i8, 512 threads = 8 waves (2M x 4N). Same XOR swizzle,
// staging map, vmcnt(4) at phases 3/7. 16 iters x 8 phases; 16 MFMA/phase.
// Epilogue: out = sx[row] * sw[col] * (float)acc_i32.
#define VMW asm volatile("s_waitcnt vmcnt(4)" ::: "memory")
#define NOW ((void)0)

#define STG(gbase, koff, ldsoff) do { \
    gload_lds16((gbase) + (size_t)(koff), &lds[(ldsoff) + dst0]); \
    gload_lds16((gbase) + (size_t)(koff) + (size_t)64 * K_DIM, \
                &lds[(ldsoff) + dst0 + 4096]); \
  } while (0)

#define PHASE(qq, PAR, TAIL, ...) { \
    if ((qq) == 0) { \
      const int bb = 32768 + (PAR) * 16384 + (wc >> 1) * 8192 + ((wc & 1) * 64 + rl) * 64; \
      _Pragma("unroll") \
      for (int n = 0; n < 4; ++n) { \
        bfr[n][0] = *(const i32x4*)&lds[bb + n * 1024 + slot0]; \
        bfr[n][1] = *(const i32x4*)&lds[bb + n * 1024 + slot1]; \
      } \
    } \
    { const int ab = (PAR) * 16384 + wr * 8192 + ((qq) * 32 + rl) * 64; \
      af00 = *(const i32x4*)&lds[ab + slot0]; \
      af01 = *(const i32x4*)&lds[ab + slot1]; \
      af10 = *(const i32x4*)&lds[ab + 1024 + slot0]; \
      af11 = *(const i32x4*)&lds[ab + 1024 + slot1]; } \
    __VA_ARGS__; \
    asm volatile("s_barrier" ::: "memory"); \
    __builtin_amdgcn_s_setprio(1); \
    _Pragma("unroll") \
    for (int n = 0; n < 4; ++n) { \
      acc[(qq)*2][n]     = mfma_i8(af01, bfr[n][1], \
                             mfma_i8(af00, bfr[n][0], acc[(qq)*2][n])); \
      acc[(qq)*2 + 1][n] = mfma_i8(af11, bfr[n][1], \
                             mfma_i8(af10, bfr[n][0], acc[(qq)*2 + 1][n])); \
    } \
    __builtin_amdgcn_s_setprio(0); \
    TAIL; \
    asm volatile("s_barrier" ::: "memory"); \
  }

__global__ __launch_bounds__(512) void k_gemm(const signed char* __restrict__ A,
                                              const signed char* __restrict__ Bw,
                                              const float* __restrict__ sxf,
                                              const float* __restrict__ swf,
                                              float* __restrict__ C) {
  __shared__ unsigned short lds[65536];   // 128 KiB
  const int tid = threadIdx.x;
  const int l = tid & 63, w = tid >> 6;
  const int wr = w >> 2, wc = w & 3;      // 2M x 4N waves
  const int rl = l & 15, hi = l >> 4;

  // XCD-aware remap: 8x8 tile chunk per XCD (proven R9)
  const int bid = blockIdx.x;
  const int xcd = bid & 7, jj = bid >> 3;
  const int brow = ((xcd >> 1) * 8 + (jj >> 3)) * 256;   // 32 m-tiles
  const int bcol = ((xcd & 1) * 8 + (jj & 7)) * 256;     // 16 n-tiles

  // staging: per-thread source with inverse swizzle, linear LDS dest
  const int row0 = tid >> 3;                                // 0..63
  const int gc = ((tid & 7) ^ (row0 & 7)) * 16;             // pre-swizzled byte col
  const signed char* pa  = A  + (size_t)(brow + row0) * K_DIM + gc;
  const signed char* pa2 = pa + (size_t)128 * K_DIM;
  const signed char* pb  = Bw + (size_t)(bcol + row0) * K_DIM + gc;
  const signed char* pb2 = pb + (size_t)128 * K_DIM;
  const int dst0 = tid * 8;   // ushort units = 16B per thread

  // swizzled ds_read slot offsets (ushort units; row&7 == rl&7 for our rows)
  const int rb7 = rl & 7;
  const int slot0 = ((0 + hi) ^ rb7) << 3;   // kh=0 (k 0..63)
  const int slot1 = ((4 + hi) ^ rb7) << 3;   // kh=1 (k 64..127)

  i32x4 acc[8][4] = {};

  // ---- prologue: stage B(0), A(0), B(1) ----
  STG(pb,  0,   32768);           // B(0).h0
  STG(pb2, 0,   32768 + 8192);    // B(0).h1
  STG(pa,  0,   0);               // A(0).h0
  STG(pa2, 0,   8192);            // A(0).h1
  STG(pb,  128, 32768 + 16384);          // B(1).h0
  STG(pb2, 128, 32768 + 16384 + 8192);   // B(1).h1
  asm volatile("s_waitcnt vmcnt(4)" ::: "memory");
  asm volatile("s_barrier" ::: "memory");

  for (int it = 0; it < 16; ++it) {
    const int k0  = it * 256;
    const int kA1 = k0 + 128;                     // tile 2it+1
    const int kN0 = (k0 + 256) & (K_DIM - 1);     // tile 2it+2 (wrapped at end)
    const int kN1 = (k0 + 384) & (K_DIM - 1);     // tile 2it+3
    i32x4 bfr[4][2];
    i32x4 af00, af01, af10, af11;
    PHASE(0, 0, NOW, STG(pa,  kA1, 16384))                 // stage A(2it+1).h0
    PHASE(1, 0, NOW, STG(pa2, kA1, 16384 + 8192))          // A(2it+1).h1
    PHASE(2, 0, NOW, STG(pb,  kN0, 32768))                 // B(2it+2).h0
    PHASE(3, 0, VMW, STG(pb2, kN0, 32768 + 8192))          // B(2it+2).h1
    PHASE(0, 1, NOW, STG(pa,  kN0, 0))                     // A(2it+2).h0
    PHASE(1, 1, NOW, STG(pa2, kN0, 8192))                  // A(2it+2).h1
    PHASE(2, 1, NOW, STG(pb,  kN1, 32768 + 16384))         // B(2it+3).h0
    PHASE(3, 1, VMW, STG(pb2, kN1, 32768 + 16384 + 8192))  // B(2it+3).h1
  }

  // epilogue: dequant out = sx[row] * sw[col] * acc
  float swv[4];
  #pragma unroll
  for (int n = 0; n < 4; ++n) swv[n] = swf[bcol + wc * 64 + n * 16 + rl];
  #pragma unroll
  for (int m = 0; m < 8; ++m) {
    const int row = brow + wr * 128 + m * 16 + hi * 4;
    float sxr[4];
    #pragma unroll
    for (int r = 0; r < 4; ++r) sxr[r] = sxf[row + r];
    #pragma unroll
    for (int n = 0; n < 4; ++n) {
      const int col = bcol + wc * 64 + n * 16 + rl;
      #pragma unroll
      for (int r = 0; r < 4; ++r)
        C[(size_t)(row + r) * N_DIM + col] = (float)acc[m][n][r] * sxr[r] * swv[n];
    }
  }
}

extern "C" void kernel_launch(void* const* d_in, const int* in_sizes, int n_in,
                              void* d_out, int out_size, void* d_ws, size_t ws_size,
                              hipStream_t stream) {
  const float* x     = (const float*)d_in[0];
  const int*   idxp  = (const int*)d_in[1];
  const float* cb    = (const float*)d_in[2];
  const float* norms = (const float*)d_in[3];
  const float* rot   = (const float*)d_in[4];
  float* out = (float*)d_out;

  unsigned short* weff = (unsigned short*)d_ws;                            // 32 MiB @ 0
  signed char* qw  = (signed char*)d_ws + 33554432;                        // 16 MiB
  signed char* qx  = (signed char*)d_ws + 50331648;                        // 32 MiB
  float* sxf    = (float*)((char*)d_ws + 83886080);                        // 32 KiB
  float* swpart = (float*)((char*)d_ws + 83918848);                        // 512 KiB
  float* swf    = (float*)((char*)d_ws + 84443136);                        // 16 KiB

  k_prep<<<3072, 256, 0, stream>>>(x, qx, sxf, idxp, cb, norms, rot, weff, swpart);
  k_wquant<<<4096, 256, 0, stream>>>(weff, swpart, qw, swf);
  k_gemm<<<512, 512, 0, stream>>>(qx, qw, sxf, swf, out);
}